// Round 2
// baseline (897.683 us; speedup 1.0000x reference)
//
#include <hip/hip_runtime.h>

// AttentionAgg: segment-softmax attention aggregation.
//   score = M @ a; smax = segmax(score,dest); ex = exp(score-smax[dest])
//   denom = segsum(ex,dest); alpha = ex/denom[dest]
//   Mv = segsum(alpha*M, dest); out = Mv[src] - alpha[rev]*M[rev]
//
// E = 800000, d = 64, N = 50000 (dim_size is a device scalar; hardcoded).
//
// Structure (this round): all row-kernels use 16 lanes/row + float4 (16B/lane)
// instead of 64 lanes/row + 4B/lane (round-1 k_score_max ran at 9.7% HBM peak
// from scalar-load overhead). k_denom folded into k_scatter (accumulate
// unnormalized U and denom together); k_norm normalizes once per node.

#define THREADS 256

// Monotonic unsigned encoding of float for atomicMax-based segment max.
// enc(-inf)=0x007FFFFF > 0, so a 0-initialized buffer acts as -infinity.
__device__ __forceinline__ unsigned enc_f(float x) {
    unsigned b = __float_as_uint(x);
    return (b & 0x80000000u) ? ~b : (b | 0x80000000u);
}
__device__ __forceinline__ float dec_f(unsigned e) {
    return __uint_as_float((e & 0x80000000u) ? (e ^ 0x80000000u) : ~e);
}

// K1: 16 lanes per edge, float4 loads. score[e]=dot(M[e,:],a); segment max.
__global__ void k_score_max(const float4* __restrict__ M4,
                            const float4* __restrict__ a4,
                            const int* __restrict__ dest,
                            float* __restrict__ score,
                            unsigned* __restrict__ smax_enc,
                            int E) {
    long long gid = (long long)blockIdx.x * blockDim.x + threadIdx.x;
    int e  = (int)(gid >> 4);
    int sl = (int)(gid & 15);
    if (e >= E) return;
    float4 m  = M4[(size_t)e * 16 + sl];
    float4 av = a4[sl];                        // 256B array, L1-resident
    float v = m.x * av.x + m.y * av.y + m.z * av.z + m.w * av.w;
    v += __shfl_xor(v, 1, 64);
    v += __shfl_xor(v, 2, 64);
    v += __shfl_xor(v, 4, 64);
    v += __shfl_xor(v, 8, 64);                 // offsets <16: stays in 16-group
    if (sl == 0) {
        score[e] = v;
        atomicMax(&smax_enc[dest[e]], enc_f(v));
    }
}

// K2: 16 lanes per edge. ex = exp(score - smax[dest]); store ex;
// denom[dest] += ex (leader); U[dest,:] += ex * M[e,:] (4 atomics/lane).
__global__ void k_scatter(const float4* __restrict__ M4,
                          const float* __restrict__ score,
                          const int* __restrict__ dest,
                          const unsigned* __restrict__ smax_enc,
                          float* __restrict__ ex_out,
                          float* __restrict__ denom,
                          float* __restrict__ U,
                          int E) {
    long long gid = (long long)blockIdx.x * blockDim.x + threadIdx.x;
    int e  = (int)(gid >> 4);
    int sl = (int)(gid & 15);
    if (e >= E) return;
    int dn = dest[e];
    float ex = 0.f;
    if (sl == 0) {
        ex = expf(score[e] - dec_f(smax_enc[dn]));
        ex_out[e] = ex;
        atomicAdd(&denom[dn], ex);
    }
    ex = __shfl(ex, 0, 16);                    // broadcast within 16-group
    float4 m = M4[(size_t)e * 16 + sl];
    float* dst = &U[(size_t)dn * 64 + sl * 4];
    atomicAdd(dst + 0, ex * m.x);
    atomicAdd(dst + 1, ex * m.y);
    atomicAdd(dst + 2, ex * m.z);
    atomicAdd(dst + 3, ex * m.w);
}

// K3: 16 lanes per node. Mv = U * (1/denom) in place; store inv_denom.
__global__ void k_norm(float4* __restrict__ U4,
                       const float* __restrict__ denom,
                       float* __restrict__ inv_denom,
                       int N) {
    long long gid = (long long)blockIdx.x * blockDim.x + threadIdx.x;
    int n  = (int)(gid >> 4);
    int sl = (int)(gid & 15);
    if (n >= N) return;
    float dv = denom[n];
    float inv = dv > 0.f ? 1.0f / dv : 0.0f;   // empty-node guard (0*inf=NaN)
    if (sl == 0) inv_denom[n] = inv;
    float4 u = U4[(size_t)n * 16 + sl];
    u.x *= inv; u.y *= inv; u.z *= inv; u.w *= inv;
    U4[(size_t)n * 16 + sl] = u;
}

// K4: 16 lanes per edge. out = Mv[src] - (ex[r]*inv_denom[dest[r]]) * M[r].
__global__ void k_out(const float4* __restrict__ M4,
                      const float4* __restrict__ Mv4,
                      const float* __restrict__ ex,
                      const float* __restrict__ inv_denom,
                      const int* __restrict__ src,
                      const int* __restrict__ dest,
                      const int* __restrict__ rev,
                      float4* __restrict__ out4,
                      int E) {
    long long gid = (long long)blockIdx.x * blockDim.x + threadIdx.x;
    int e  = (int)(gid >> 4);
    int sl = (int)(gid & 15);
    if (e >= E) return;
    int s = 0, r = 0; float al = 0.f;
    if (sl == 0) {
        s = src[e];
        r = rev[e];
        al = ex[r] * inv_denom[dest[r]];       // ex/dest: 3.2MB, L2-resident
    }
    s  = __shfl(s, 0, 16);
    r  = __shfl(r, 0, 16);
    al = __shfl(al, 0, 16);
    float4 mv = Mv4[(size_t)s * 16 + sl];
    float4 mr = M4[(size_t)r * 16 + sl];
    float4 o;
    o.x = mv.x - al * mr.x;
    o.y = mv.y - al * mr.y;
    o.z = mv.z - al * mr.z;
    o.w = mv.w - al * mr.w;
    out4[(size_t)e * 16 + sl] = o;
}

extern "C" void kernel_launch(void* const* d_in, const int* in_sizes, int n_in,
                              void* d_out, int out_size, void* d_ws, size_t ws_size,
                              hipStream_t stream) {
    const float* M  = (const float*)d_in[0];
    const float* a  = (const float*)d_in[1];
    const int* eidx = (const int*)d_in[2];   // [2, E] flat: src row then dest row
    const int* rev  = (const int*)d_in[3];
    const int N = 50000;
    const int E = in_sizes[3];

    const int* src  = eidx;
    const int* dest = eidx + E;

    // Workspace: score[E] | ex[E] | smax_enc[N] | denom[N] | inv_denom[N] | U[N*64]
    char* ws = (char*)d_ws;
    float*    score     = (float*)ws;    ws += (size_t)E * 4;
    float*    ex        = (float*)ws;    ws += (size_t)E * 4;
    unsigned* smax_enc  = (unsigned*)ws; ws += (size_t)N * 4;
    float*    denom     = (float*)ws;    ws += (size_t)N * 4;
    float*    inv_denom = (float*)ws;    ws += (size_t)N * 4;
    float*    U         = (float*)ws;    ws += (size_t)N * 64 * 4;

    // Re-zero accumulators every call (replay-safe / idempotent).
    hipMemsetAsync(smax_enc, 0, (size_t)N * 4, stream);
    hipMemsetAsync(denom,    0, (size_t)N * 4, stream);
    hipMemsetAsync(U,        0, (size_t)N * 64 * 4, stream);

    long long tE16 = (long long)E * 16;
    int blocksE16 = (int)((tE16 + THREADS - 1) / THREADS);
    int blocksN16 = (int)(((long long)N * 16 + THREADS - 1) / THREADS);

    k_score_max<<<blocksE16, THREADS, 0, stream>>>(
        (const float4*)M, (const float4*)a, dest, score, smax_enc, E);
    k_scatter<<<blocksE16, THREADS, 0, stream>>>(
        (const float4*)M, score, dest, smax_enc, ex, denom, U, E);
    k_norm<<<blocksN16, THREADS, 0, stream>>>(
        (float4*)U, denom, inv_denom, N);
    k_out<<<blocksE16, THREADS, 0, stream>>>(
        (const float4*)M, (const float4*)U, ex, inv_denom, src, dest, rev,
        (float4*)d_out, E);
}

// Round 3
// 376.394 us; speedup vs baseline: 2.3850x; 2.3850x over previous
//
#include <hip/hip_runtime.h>
#include <float.h>

// AttentionAgg via destination-CSR (no float atomics).
//   score = M @ a; smax = segmax(score,dest); ex = exp(score-smax[dest])
//   denom = segsum(ex,dest); alpha = ex/denom[dest]
//   Mv = segsum(alpha*M, dest); out = Mv[src] - alpha[rev]*M[rev]
//
// E = 800000, d = 64, N = 50000 (dim_size is a device scalar; hardcoded).
//
// Round-2 lesson: 51.2M scattered f32 atomicAdds produced 828 MB of
// memory-side RMW traffic (atomics resolve past the per-XCD L2s) -> 700us.
// This round builds a CSR over dest (histogram + scan + bucket fill, int
// atomics only) and aggregates gather-side, one wave per node, accumulating
// in registers and writing each Mv row exactly once.

#define THREADS 256

// ---------------------------------------------------------------------------
// K1: 16 lanes/edge, float4 loads. score[e]=dot(M[e,:],a); histogram dest.
__global__ void k_score_hist(const float4* __restrict__ M4,
                             const float4* __restrict__ a4,
                             const int* __restrict__ dest,
                             float* __restrict__ score,
                             int* __restrict__ counts,
                             int E) {
    long long gid = (long long)blockIdx.x * blockDim.x + threadIdx.x;
    int e  = (int)(gid >> 4);
    int sl = (int)(gid & 15);
    if (e >= E) return;
    float4 m  = M4[(size_t)e * 16 + sl];
    float4 av = a4[sl];                        // 256B, L1-resident
    float v = m.x * av.x + m.y * av.y + m.z * av.z + m.w * av.w;
    v += __shfl_xor(v, 1, 64);
    v += __shfl_xor(v, 2, 64);
    v += __shfl_xor(v, 4, 64);
    v += __shfl_xor(v, 8, 64);
    if (sl == 0) {
        score[e] = v;
        atomicAdd(&counts[dest[e]], 1);
    }
}

// ---------------------------------------------------------------------------
// K2: single-workgroup exclusive scan of counts[N] -> offsets[N+1], cursor[N].
__global__ void k_scan(const int* __restrict__ counts,
                       int* __restrict__ offsets,
                       int* __restrict__ cursor,
                       int N) {
    __shared__ int partial[1024];
    int t = threadIdx.x;
    int chunk = (N + 1023) / 1024;
    int b = t * chunk;
    int e = min(b + chunk, N);
    int s = 0;
    for (int i = b; i < e; ++i) s += counts[i];
    partial[t] = s;
    __syncthreads();
    // Hillis-Steele inclusive scan over 1024 partials
    for (int off = 1; off < 1024; off <<= 1) {
        int v = (t >= off) ? partial[t - off] : 0;
        __syncthreads();
        partial[t] += v;
        __syncthreads();
    }
    int run = (t == 0) ? 0 : partial[t - 1];
    for (int i = b; i < e; ++i) {
        offsets[i] = run;
        cursor[i]  = run;
        run += counts[i];
    }
    if (t == 1023) offsets[N] = run;   // total == E
}

// ---------------------------------------------------------------------------
// K3: bucket fill. sorted_eid[cursor[dest[e]]++] = e.
__global__ void k_fill(const int* __restrict__ dest,
                       int* __restrict__ cursor,
                       int* __restrict__ sorted_eid,
                       int E) {
    int e = blockIdx.x * blockDim.x + threadIdx.x;
    if (e >= E) return;
    int pos = atomicAdd(&cursor[dest[e]], 1);
    sorted_eid[pos] = e;
}

// ---------------------------------------------------------------------------
// K4: one wave per node. Pass A: wave-max of scores. Pass B: 4 groups x 16
// lanes accumulate ex*M rows in registers; cross-group shfl reduce; write
// Mv row once. Also writes smax_f[n], inv_denom[n].
__global__ void k_aggregate(const float4* __restrict__ M4,
                            const float* __restrict__ score,
                            const int* __restrict__ sorted_eid,
                            const int* __restrict__ offsets,
                            float4* __restrict__ Mv4,
                            float* __restrict__ smax_f,
                            float* __restrict__ inv_denom,
                            int N) {
    long long gid = (long long)blockIdx.x * blockDim.x + threadIdx.x;
    int n    = (int)(gid >> 6);
    int lane = (int)(gid & 63);
    if (n >= N) return;
    int beg = offsets[n];
    int end = offsets[n + 1];

    // Pass A: segment max (all 64 lanes gather scores)
    float m = -FLT_MAX;
    for (int i = beg + lane; i < end; i += 64)
        m = fmaxf(m, score[sorted_eid[i]]);
    #pragma unroll
    for (int off = 32; off; off >>= 1)
        m = fmaxf(m, __shfl_xor(m, off, 64));

    // Pass B: 4 edge-groups of 16 lanes; each lane holds a float4 slice.
    int grp = lane >> 4;
    int sl  = lane & 15;
    float4 acc = make_float4(0.f, 0.f, 0.f, 0.f);
    float dsum = 0.f;
    for (int i = beg + grp; i < end; i += 4) {
        int e = sorted_eid[i];
        float ex = expf(score[e] - m);
        if (sl == 0) dsum += ex;
        float4 mm = M4[(size_t)e * 16 + sl];
        acc.x += ex * mm.x;
        acc.y += ex * mm.y;
        acc.z += ex * mm.z;
        acc.w += ex * mm.w;
    }
    // reduce the 4 groups onto lanes 0..15
    acc.x += __shfl_xor(acc.x, 16, 64);  acc.x += __shfl_xor(acc.x, 32, 64);
    acc.y += __shfl_xor(acc.y, 16, 64);  acc.y += __shfl_xor(acc.y, 32, 64);
    acc.z += __shfl_xor(acc.z, 16, 64);  acc.z += __shfl_xor(acc.z, 32, 64);
    acc.w += __shfl_xor(acc.w, 16, 64);  acc.w += __shfl_xor(acc.w, 32, 64);
    dsum  += __shfl_xor(dsum, 16, 64);
    dsum  += __shfl_xor(dsum, 32, 64);
    float dtot = __shfl(dsum, 0, 64);
    float inv  = dtot > 0.f ? 1.0f / dtot : 0.0f;
    if (lane == 0) {
        smax_f[n]    = m;
        inv_denom[n] = inv;
    }
    if (lane < 16) {
        float4 o;
        o.x = acc.x * inv; o.y = acc.y * inv;
        o.z = acc.z * inv; o.w = acc.w * inv;
        Mv4[(size_t)n * 16 + lane] = o;
    }
}

// ---------------------------------------------------------------------------
// K5: per-edge alpha[e] = exp(score[e]-smax[dest[e]]) * inv_denom[dest[e]].
__global__ void k_alpha(const float* __restrict__ score,
                        const int* __restrict__ dest,
                        const float* __restrict__ smax_f,
                        const float* __restrict__ inv_denom,
                        float* __restrict__ alpha,
                        int E) {
    int e = blockIdx.x * blockDim.x + threadIdx.x;
    if (e >= E) return;
    int dn = dest[e];
    alpha[e] = expf(score[e] - smax_f[dn]) * inv_denom[dn];
}

// ---------------------------------------------------------------------------
// K6: 16 lanes/edge. out = Mv[src] - alpha[rev] * M[rev].
__global__ void k_out(const float4* __restrict__ M4,
                      const float4* __restrict__ Mv4,
                      const float* __restrict__ alpha,
                      const int* __restrict__ src,
                      const int* __restrict__ rev,
                      float4* __restrict__ out4,
                      int E) {
    long long gid = (long long)blockIdx.x * blockDim.x + threadIdx.x;
    int e  = (int)(gid >> 4);
    int sl = (int)(gid & 15);
    if (e >= E) return;
    int s = 0, r = 0; float al = 0.f;
    if (sl == 0) {
        s  = src[e];
        r  = rev[e];
        al = alpha[r];
    }
    s  = __shfl(s, 0, 16);
    r  = __shfl(r, 0, 16);
    al = __shfl(al, 0, 16);
    float4 mv = Mv4[(size_t)s * 16 + sl];
    float4 mr = M4[(size_t)r * 16 + sl];
    float4 o;
    o.x = mv.x - al * mr.x;
    o.y = mv.y - al * mr.y;
    o.z = mv.z - al * mr.z;
    o.w = mv.w - al * mr.w;
    out4[(size_t)e * 16 + sl] = o;
}

// ---------------------------------------------------------------------------
extern "C" void kernel_launch(void* const* d_in, const int* in_sizes, int n_in,
                              void* d_out, int out_size, void* d_ws, size_t ws_size,
                              hipStream_t stream) {
    const float* M  = (const float*)d_in[0];
    const float* a  = (const float*)d_in[1];
    const int* eidx = (const int*)d_in[2];   // [2, E] flat: src row, dest row
    const int* rev  = (const int*)d_in[3];
    const int N = 50000;
    const int E = in_sizes[3];

    const int* src  = eidx;
    const int* dest = eidx + E;

    // Workspace layout (Mv first for 16B alignment of float4 array):
    //  Mv[N*64] | score[E] | alpha[E] | sorted_eid[E] | counts[N] |
    //  offsets[N+1] | cursor[N] | smax_f[N] | inv_denom[N]        ~= 20.3 MB
    char* ws = (char*)d_ws;
    float* Mv        = (float*)ws; ws += (size_t)N * 64 * 4;
    float* score     = (float*)ws; ws += (size_t)E * 4;
    float* alpha     = (float*)ws; ws += (size_t)E * 4;
    int*   sorted_eid= (int*)ws;   ws += (size_t)E * 4;
    int*   counts    = (int*)ws;   ws += (size_t)N * 4;
    int*   offsets   = (int*)ws;   ws += (size_t)(N + 1) * 4;
    int*   cursor    = (int*)ws;   ws += (size_t)N * 4;
    float* smax_f    = (float*)ws; ws += (size_t)N * 4;
    float* inv_denom = (float*)ws; ws += (size_t)N * 4;

    // Idempotent per call: only counts needs re-zeroing (scan rewrites
    // offsets/cursor, aggregate rewrites Mv/smax/inv, fill rewrites sorted).
    hipMemsetAsync(counts, 0, (size_t)N * 4, stream);

    long long tE16 = (long long)E * 16;
    int blocksE16 = (int)((tE16 + THREADS - 1) / THREADS);
    int blocksE   = (E + THREADS - 1) / THREADS;
    int blocksN64 = (int)(((long long)N * 64 + THREADS - 1) / THREADS);

    k_score_hist<<<blocksE16, THREADS, 0, stream>>>(
        (const float4*)M, (const float4*)a, dest, score, counts, E);
    k_scan<<<1, 1024, 0, stream>>>(counts, offsets, cursor, N);
    k_fill<<<blocksE, THREADS, 0, stream>>>(dest, cursor, sorted_eid, E);
    k_aggregate<<<blocksN64, THREADS, 0, stream>>>(
        (const float4*)M, score, sorted_eid, offsets,
        (float4*)Mv, smax_f, inv_denom, N);
    k_alpha<<<blocksE, THREADS, 0, stream>>>(
        score, dest, smax_f, inv_denom, alpha, E);
    k_out<<<blocksE16, THREADS, 0, stream>>>(
        (const float4*)M, (const float4*)Mv, alpha, src, rev,
        (float4*)d_out, E);
}

// Round 6
// 363.261 us; speedup vs baseline: 2.4712x; 1.0362x over previous
//
#include <hip/hip_runtime.h>
#include <float.h>

// AttentionAgg via destination-CSR (no float atomics).
//   score = M @ a; smax = segmax(score,dest); ex = exp(score-smax[dest])
//   denom = segsum(ex,dest); alpha = ex/denom[dest]
//   Mv = segsum(alpha*M, dest); out = Mv[src] - alpha[rev]*M[rev]
//
// E = 800000, d = 64, N = 50000 (dim_size is a device scalar; hardcoded).
//
// Round-5 lesson: __shfl inside a loop whose trip count differs across the
// wave's 16-lane groups reads from INACTIVE source lanes (ds_bpermute data
// from masked lanes is undefined) -> garbage eid/ex for deg % 4 != 0 nodes.
// Fix: wave-uniform trip count, shfl with all lanes active, predicate only
// the gather/accumulate.

#define THREADS 256

typedef float f32x4 __attribute__((ext_vector_type(4)));

// ---------------------------------------------------------------------------
// K0: zero counts[N] (N multiple of 4). Replaces hipMemsetAsync.
__global__ void k_zero(int4* __restrict__ p, int n4) {
    int i = blockIdx.x * blockDim.x + threadIdx.x;
    if (i < n4) p[i] = make_int4(0, 0, 0, 0);
}

// ---------------------------------------------------------------------------
// K1: 16 lanes/edge, float4 loads. score[e]=dot(M[e,:],a); histogram dest.
__global__ void k_score_hist(const float4* __restrict__ M4,
                             const float4* __restrict__ a4,
                             const int* __restrict__ dest,
                             float* __restrict__ score,
                             int* __restrict__ counts,
                             int E) {
    long long gid = (long long)blockIdx.x * blockDim.x + threadIdx.x;
    int e  = (int)(gid >> 4);
    int sl = (int)(gid & 15);
    if (e >= E) return;
    float4 m  = M4[(size_t)e * 16 + sl];
    float4 av = a4[sl];                        // 256B, L1-resident
    float v = m.x * av.x + m.y * av.y + m.z * av.z + m.w * av.w;
    v += __shfl_xor(v, 1, 64);
    v += __shfl_xor(v, 2, 64);
    v += __shfl_xor(v, 4, 64);
    v += __shfl_xor(v, 8, 64);
    if (sl == 0) {
        score[e] = v;
        atomicAdd(&counts[dest[e]], 1);
    }
}

// ---------------------------------------------------------------------------
// K2: single-workgroup exclusive scan of counts[N] -> offsets[N+1], cursor[N].
__global__ void k_scan(const int* __restrict__ counts,
                       int* __restrict__ offsets,
                       int* __restrict__ cursor,
                       int N) {
    __shared__ int partial[1024];
    int t = threadIdx.x;
    int chunk = (N + 1023) / 1024;
    int b = t * chunk;
    int e = min(b + chunk, N);
    int s = 0;
    for (int i = b; i < e; ++i) s += counts[i];
    partial[t] = s;
    __syncthreads();
    // Hillis-Steele inclusive scan over 1024 partials
    for (int off = 1; off < 1024; off <<= 1) {
        int v = (t >= off) ? partial[t - off] : 0;
        __syncthreads();
        partial[t] += v;
        __syncthreads();
    }
    int run = (t == 0) ? 0 : partial[t - 1];
    for (int i = b; i < e; ++i) {
        offsets[i] = run;
        cursor[i]  = run;
        run += counts[i];
    }
    if (t == 1023) offsets[N] = run;   // total == E
}

// ---------------------------------------------------------------------------
// K3: bucket fill. sorted_eid[cursor[dest[e]]++] = e.
__global__ void k_fill(const int* __restrict__ dest,
                       int* __restrict__ cursor,
                       int* __restrict__ sorted_eid,
                       int E) {
    int e = blockIdx.x * blockDim.x + threadIdx.x;
    if (e >= E) return;
    int pos = atomicAdd(&cursor[dest[e]], 1);
    sorted_eid[pos] = e;
}

// ---------------------------------------------------------------------------
// K4: one wave per node.
// Fast path (deg<=64): each lane loads one (eid, score) pair; wave-reduce max
// and exp-sum in registers; weighted pass uses a WAVE-UNIFORM trip count so
// every __shfl executes with all 64 lanes active (defined data), and only the
// gather/accumulate is predicated. Fallback (deg>64): two-pass gather.
__global__ void k_aggregate(const float4* __restrict__ M4,
                            const float* __restrict__ score,
                            const int* __restrict__ sorted_eid,
                            const int* __restrict__ offsets,
                            float4* __restrict__ Mv4,
                            float* __restrict__ smax_f,
                            float* __restrict__ inv_denom,
                            int N) {
    long long gid = (long long)blockIdx.x * blockDim.x + threadIdx.x;
    int n    = (int)(gid >> 6);
    int lane = (int)(gid & 63);
    if (n >= N) return;
    int beg = offsets[n];
    int end = offsets[n + 1];
    int deg = end - beg;
    int grp = lane >> 4;
    int sl  = lane & 15;

    float4 acc = make_float4(0.f, 0.f, 0.f, 0.f);
    float m, dtot;

    if (deg <= 64) {
        int   eid = 0;
        float sc  = -FLT_MAX;
        if (lane < deg) {
            eid = sorted_eid[beg + lane];
            sc  = score[eid];
        }
        m = sc;
        #pragma unroll
        for (int off = 32; off; off >>= 1)
            m = fmaxf(m, __shfl_xor(m, off, 64));
        float exr = (lane < deg) ? expf(sc - m) : 0.f;
        float ds  = exr;
        #pragma unroll
        for (int off = 32; off; off >>= 1)
            ds += __shfl_xor(ds, off, 64);
        dtot = ds;
        // wave-uniform trip count: iters same for all lanes; shfl src lane
        // i = grp + 4k <= 3 + 4*15 = 63, always in range, always active.
        int iters = (deg + 3) >> 2;
        for (int k = 0; k < iters; ++k) {
            int i = grp + 4 * k;
            float ex = __shfl(exr, i, 64);
            int   e  = __shfl(eid, i, 64);
            if (i < deg) {
                float4 mm = M4[(size_t)e * 16 + sl];
                acc.x += ex * mm.x;
                acc.y += ex * mm.y;
                acc.z += ex * mm.z;
                acc.w += ex * mm.w;
            }
        }
    } else {
        m = -FLT_MAX;
        for (int i = beg + lane; i < end; i += 64)
            m = fmaxf(m, score[sorted_eid[i]]);
        #pragma unroll
        for (int off = 32; off; off >>= 1)
            m = fmaxf(m, __shfl_xor(m, off, 64));
        float dsum = 0.f;
        for (int i = beg + grp; i < end; i += 4) {
            int e = sorted_eid[i];
            float ex = expf(score[e] - m);
            if (sl == 0) dsum += ex;
            float4 mm = M4[(size_t)e * 16 + sl];
            acc.x += ex * mm.x;
            acc.y += ex * mm.y;
            acc.z += ex * mm.z;
            acc.w += ex * mm.w;
        }
        dsum += __shfl_xor(dsum, 16, 64);
        dsum += __shfl_xor(dsum, 32, 64);
        dtot = __shfl(dsum, 0, 64);
    }

    // reduce the 4 groups onto lanes 0..15
    acc.x += __shfl_xor(acc.x, 16, 64);  acc.x += __shfl_xor(acc.x, 32, 64);
    acc.y += __shfl_xor(acc.y, 16, 64);  acc.y += __shfl_xor(acc.y, 32, 64);
    acc.z += __shfl_xor(acc.z, 16, 64);  acc.z += __shfl_xor(acc.z, 32, 64);
    acc.w += __shfl_xor(acc.w, 16, 64);  acc.w += __shfl_xor(acc.w, 32, 64);

    float inv = dtot > 0.f ? 1.0f / dtot : 0.0f;  // empty/zero guard
    if (lane == 0) {
        smax_f[n]    = m;
        inv_denom[n] = inv;
    }
    if (lane < 16) {
        float4 o;
        o.x = acc.x * inv; o.y = acc.y * inv;
        o.z = acc.z * inv; o.w = acc.w * inv;
        Mv4[(size_t)n * 16 + lane] = o;
    }
}

// ---------------------------------------------------------------------------
// K5: per-edge alpha[e] = exp(score[e]-smax[dest[e]]) * inv_denom[dest[e]].
__global__ void k_alpha(const float* __restrict__ score,
                        const int* __restrict__ dest,
                        const float* __restrict__ smax_f,
                        const float* __restrict__ inv_denom,
                        float* __restrict__ alpha,
                        int E) {
    int e = blockIdx.x * blockDim.x + threadIdx.x;
    if (e >= E) return;
    int dn = dest[e];
    alpha[e] = expf(score[e] - smax_f[dn]) * inv_denom[dn];
}

// ---------------------------------------------------------------------------
// K6: 16 lanes/edge. out = Mv[src] - alpha[rev] * M[rev]. Nontemporal store
// (native clang vector type) so the 205MB out-stream doesn't evict M from L3
// (we gather M[rev] here).
__global__ void k_out(const float4* __restrict__ M4,
                      const float4* __restrict__ Mv4,
                      const float* __restrict__ alpha,
                      const int* __restrict__ src,
                      const int* __restrict__ rev,
                      f32x4* __restrict__ out4,
                      int E) {
    long long gid = (long long)blockIdx.x * blockDim.x + threadIdx.x;
    int e  = (int)(gid >> 4);
    int sl = (int)(gid & 15);
    if (e >= E) return;
    int s = 0, r = 0; float al = 0.f;
    if (sl == 0) {
        s  = src[e];
        r  = rev[e];
        al = alpha[r];
    }
    s  = __shfl(s, 0, 16);
    r  = __shfl(r, 0, 16);
    al = __shfl(al, 0, 16);
    float4 mv = Mv4[(size_t)s * 16 + sl];
    float4 mr = M4[(size_t)r * 16 + sl];
    f32x4 o;
    o.x = mv.x - al * mr.x;
    o.y = mv.y - al * mr.y;
    o.z = mv.z - al * mr.z;
    o.w = mv.w - al * mr.w;
    __builtin_nontemporal_store(o, &out4[(size_t)e * 16 + sl]);
}

// ---------------------------------------------------------------------------
extern "C" void kernel_launch(void* const* d_in, const int* in_sizes, int n_in,
                              void* d_out, int out_size, void* d_ws, size_t ws_size,
                              hipStream_t stream) {
    const float* M  = (const float*)d_in[0];
    const float* a  = (const float*)d_in[1];
    const int* eidx = (const int*)d_in[2];   // [2, E] flat: src row, dest row
    const int* rev  = (const int*)d_in[3];
    const int N = 50000;
    const int E = in_sizes[3];

    const int* src  = eidx;
    const int* dest = eidx + E;

    // Workspace layout (Mv first for 16B alignment of float4 array):
    //  Mv[N*64] | score[E] | alpha[E] | sorted_eid[E] | counts[N] |
    //  offsets[N+1] | cursor[N] | smax_f[N] | inv_denom[N]        ~= 20.3 MB
    char* ws = (char*)d_ws;
    float* Mv        = (float*)ws; ws += (size_t)N * 64 * 4;
    float* score     = (float*)ws; ws += (size_t)E * 4;
    float* alpha     = (float*)ws; ws += (size_t)E * 4;
    int*   sorted_eid= (int*)ws;   ws += (size_t)E * 4;
    int*   counts    = (int*)ws;   ws += (size_t)N * 4;
    int*   offsets   = (int*)ws;   ws += (size_t)(N + 1) * 4;
    int*   cursor    = (int*)ws;   ws += (size_t)N * 4;
    float* smax_f    = (float*)ws; ws += (size_t)N * 4;
    float* inv_denom = (float*)ws; ws += (size_t)N * 4;

    long long tE16 = (long long)E * 16;
    int blocksE16 = (int)((tE16 + THREADS - 1) / THREADS);
    int blocksE   = (E + THREADS - 1) / THREADS;
    int blocksN64 = (int)(((long long)N * 64 + THREADS - 1) / THREADS);
    int n4        = N / 4;                       // N = 50000, multiple of 4
    int blocksZ   = (n4 + THREADS - 1) / THREADS;

    k_zero<<<blocksZ, THREADS, 0, stream>>>((int4*)counts, n4);
    k_score_hist<<<blocksE16, THREADS, 0, stream>>>(
        (const float4*)M, (const float4*)a, dest, score, counts, E);
    k_scan<<<1, 1024, 0, stream>>>(counts, offsets, cursor, N);
    k_fill<<<blocksE, THREADS, 0, stream>>>(dest, cursor, sorted_eid, E);
    k_aggregate<<<blocksN64, THREADS, 0, stream>>>(
        (const float4*)M, score, sorted_eid, offsets,
        (float4*)Mv, smax_f, inv_denom, N);
    k_alpha<<<blocksE, THREADS, 0, stream>>>(
        score, dest, smax_f, inv_denom, alpha, E);
    k_out<<<blocksE16, THREADS, 0, stream>>>(
        (const float4*)M, (const float4*)Mv, alpha, src, rev,
        (f32x4*)d_out, E);
}

// Round 7
// 266.742 us; speedup vs baseline: 3.3654x; 1.3618x over previous
//
#include <hip/hip_runtime.h>
#include <float.h>

// AttentionAgg via destination-CSR (no float atomics).
//   score = M @ a; smax = segmax(score,dest); ex = exp(score-smax[dest])
//   denom = segsum(ex,dest); alpha = ex/denom[dest]
//   Mv = segsum(alpha*M, dest); out = Mv[src] - alpha[rev]*M[rev]
//
// E = 800000, d = 64, N = 50000 (dim_size is a device scalar; hardcoded).
//
// Round-6 -> 7 deltas:
//  (1) single-WG scan replaced by k_alloc: wave prefix-sum over counts +
//      one atomicAdd per wave on a global cursor (ranges are call-order
//      dependent, but intra-node FP sum order already was, via atomic fill).
//  (2) k_alpha fused into k_aggregate (lanes already hold ex; write
//      alpha[eid] = ex*inv directly). smax/inv_denom buffers dropped.
//  (3) k_out: per-lane same-address loads (HW broadcast) instead of
//      leader-load + 3-shfl chain -- shorter latency chain.

#define THREADS 256

typedef float f32x4 __attribute__((ext_vector_type(4)));

// ---------------------------------------------------------------------------
// K0: zero counts[N] + total counter (contiguous, N+4 ints, multiple of 4).
__global__ void k_zero(int4* __restrict__ p, int n4) {
    int i = blockIdx.x * blockDim.x + threadIdx.x;
    if (i < n4) p[i] = make_int4(0, 0, 0, 0);
}

// ---------------------------------------------------------------------------
// K1: 16 lanes/edge, float4 loads. score[e]=dot(M[e,:],a); histogram dest.
__global__ void k_score_hist(const float4* __restrict__ M4,
                             const float4* __restrict__ a4,
                             const int* __restrict__ dest,
                             float* __restrict__ score,
                             int* __restrict__ counts,
                             int E) {
    long long gid = (long long)blockIdx.x * blockDim.x + threadIdx.x;
    int e  = (int)(gid >> 4);
    int sl = (int)(gid & 15);
    if (e >= E) return;
    float4 m  = M4[(size_t)e * 16 + sl];
    float4 av = a4[sl];                        // 256B, L1-resident
    float v = m.x * av.x + m.y * av.y + m.z * av.z + m.w * av.w;
    v += __shfl_xor(v, 1, 64);
    v += __shfl_xor(v, 2, 64);
    v += __shfl_xor(v, 4, 64);
    v += __shfl_xor(v, 8, 64);
    if (sl == 0) {
        score[e] = v;
        atomicAdd(&counts[dest[e]], 1);
    }
}

// ---------------------------------------------------------------------------
// K2: range allocation. Wave-level exclusive prefix over counts + one
// atomicAdd(total) per wave -> offsets[n], cursor[n]. Replaces the 1-WG scan.
__global__ void k_alloc(const int* __restrict__ counts,
                        int* __restrict__ total,
                        int* __restrict__ offsets,
                        int* __restrict__ cursor,
                        int N) {
    int n    = blockIdx.x * blockDim.x + threadIdx.x;
    int lane = threadIdx.x & 63;
    int c = (n < N) ? counts[n] : 0;
    // inclusive wave scan (all 64 lanes participate; OOB lanes carry 0)
    int x = c;
    #pragma unroll
    for (int off = 1; off < 64; off <<= 1) {
        int y = __shfl_up(x, off, 64);
        if (lane >= off) x += y;
    }
    int wsum = __shfl(x, 63, 64);
    int base = 0;
    if (lane == 63) base = atomicAdd(total, wsum);
    base = __shfl(base, 63, 64);
    if (n < N) {
        int my = base + x - c;                 // exclusive position
        offsets[n] = my;
        cursor[n]  = my;
    }
}

// ---------------------------------------------------------------------------
// K3: bucket fill. sorted_eid[cursor[dest[e]]++] = e.
__global__ void k_fill(const int* __restrict__ dest,
                       int* __restrict__ cursor,
                       int* __restrict__ sorted_eid,
                       int E) {
    int e = blockIdx.x * blockDim.x + threadIdx.x;
    if (e >= E) return;
    int pos = atomicAdd(&cursor[dest[e]], 1);
    sorted_eid[pos] = e;
}

// ---------------------------------------------------------------------------
// K4: one wave per node; writes Mv row AND per-edge alpha.
// Fast path (deg<=64): each lane loads one (eid, score); wave-reduce max and
// exp-sum in registers; weighted pass uses a WAVE-UNIFORM trip count so every
// __shfl executes with all 64 lanes active (round-5 lesson); lane writes
// alpha[eid] = ex*inv at the end. Fallback (deg>64): two-pass gather.
__global__ void k_aggregate(const float4* __restrict__ M4,
                            const float* __restrict__ score,
                            const int* __restrict__ sorted_eid,
                            const int* __restrict__ offsets,
                            const int* __restrict__ counts,
                            float4* __restrict__ Mv4,
                            float* __restrict__ alpha,
                            int N) {
    long long gid = (long long)blockIdx.x * blockDim.x + threadIdx.x;
    int n    = (int)(gid >> 6);
    int lane = (int)(gid & 63);
    if (n >= N) return;
    int beg = offsets[n];
    int deg = counts[n];
    int end = beg + deg;
    int grp = lane >> 4;
    int sl  = lane & 15;

    float4 acc = make_float4(0.f, 0.f, 0.f, 0.f);
    float m, dtot;

    if (deg <= 64) {
        int   eid = 0;
        float sc  = -FLT_MAX;
        if (lane < deg) {
            eid = sorted_eid[beg + lane];
            sc  = score[eid];
        }
        m = sc;
        #pragma unroll
        for (int off = 32; off; off >>= 1)
            m = fmaxf(m, __shfl_xor(m, off, 64));
        float exr = (lane < deg) ? expf(sc - m) : 0.f;
        float ds  = exr;
        #pragma unroll
        for (int off = 32; off; off >>= 1)
            ds += __shfl_xor(ds, off, 64);
        dtot = ds;
        float inv = dtot > 0.f ? 1.0f / dtot : 0.0f;
        if (lane < deg) alpha[eid] = exr * inv;     // fused k_alpha
        // wave-uniform trip count; shfl src lane i = grp+4k <= 63, active.
        int iters = (deg + 3) >> 2;
        for (int k = 0; k < iters; ++k) {
            int i = grp + 4 * k;
            float ex = __shfl(exr, i, 64);
            int   e  = __shfl(eid, i, 64);
            if (i < deg) {
                float4 mm = M4[(size_t)e * 16 + sl];
                acc.x += ex * mm.x;
                acc.y += ex * mm.y;
                acc.z += ex * mm.z;
                acc.w += ex * mm.w;
            }
        }
        // group-reduce onto lanes 0..15
        acc.x += __shfl_xor(acc.x, 16, 64);  acc.x += __shfl_xor(acc.x, 32, 64);
        acc.y += __shfl_xor(acc.y, 16, 64);  acc.y += __shfl_xor(acc.y, 32, 64);
        acc.z += __shfl_xor(acc.z, 16, 64);  acc.z += __shfl_xor(acc.z, 32, 64);
        acc.w += __shfl_xor(acc.w, 16, 64);  acc.w += __shfl_xor(acc.w, 32, 64);
        if (lane < 16) {
            float4 o;
            o.x = acc.x * inv; o.y = acc.y * inv;
            o.z = acc.z * inv; o.w = acc.w * inv;
            Mv4[(size_t)n * 16 + lane] = o;
        }
    } else {
        m = -FLT_MAX;
        for (int i = beg + lane; i < end; i += 64)
            m = fmaxf(m, score[sorted_eid[i]]);
        #pragma unroll
        for (int off = 32; off; off >>= 1)
            m = fmaxf(m, __shfl_xor(m, off, 64));
        float dsum = 0.f;
        for (int i = beg + grp; i < end; i += 4) {
            int e = sorted_eid[i];
            float ex = expf(score[e] - m);
            if (sl == 0) dsum += ex;
            float4 mm = M4[(size_t)e * 16 + sl];
            acc.x += ex * mm.x;
            acc.y += ex * mm.y;
            acc.z += ex * mm.z;
            acc.w += ex * mm.w;
        }
        dsum += __shfl_xor(dsum, 16, 64);
        dsum += __shfl_xor(dsum, 32, 64);
        dtot = __shfl(dsum, 0, 64);
        float inv = dtot > 0.f ? 1.0f / dtot : 0.0f;
        // second pass writes alpha (rare path; deg>64 ~never at mean deg 16)
        for (int i = beg + lane; i < end; i += 64) {
            int e = sorted_eid[i];
            alpha[e] = expf(score[e] - m) * inv;
        }
        acc.x += __shfl_xor(acc.x, 16, 64);  acc.x += __shfl_xor(acc.x, 32, 64);
        acc.y += __shfl_xor(acc.y, 16, 64);  acc.y += __shfl_xor(acc.y, 32, 64);
        acc.z += __shfl_xor(acc.z, 16, 64);  acc.z += __shfl_xor(acc.z, 32, 64);
        acc.w += __shfl_xor(acc.w, 16, 64);  acc.w += __shfl_xor(acc.w, 32, 64);
        if (lane < 16) {
            float4 o;
            o.x = acc.x * inv; o.y = acc.y * inv;
            o.z = acc.z * inv; o.w = acc.w * inv;
            Mv4[(size_t)n * 16 + lane] = o;
        }
    }
}

// ---------------------------------------------------------------------------
// K5: 16 lanes/edge. out = Mv[src] - alpha[rev] * M[rev]. Per-lane
// same-address scalar loads (HW broadcast) -- no shfl chain. Nontemporal
// store so the 205MB out-stream doesn't evict M from L3.
__global__ void k_out(const float4* __restrict__ M4,
                      const float4* __restrict__ Mv4,
                      const float* __restrict__ alpha,
                      const int* __restrict__ src,
                      const int* __restrict__ rev,
                      f32x4* __restrict__ out4,
                      int E) {
    long long gid = (long long)blockIdx.x * blockDim.x + threadIdx.x;
    int e  = (int)(gid >> 4);
    int sl = (int)(gid & 15);
    if (e >= E) return;
    int s    = src[e];
    int r    = rev[e];
    float al = alpha[r];
    float4 mv = Mv4[(size_t)s * 16 + sl];
    float4 mr = M4[(size_t)r * 16 + sl];
    f32x4 o;
    o.x = mv.x - al * mr.x;
    o.y = mv.y - al * mr.y;
    o.z = mv.z - al * mr.z;
    o.w = mv.w - al * mr.w;
    __builtin_nontemporal_store(o, &out4[(size_t)e * 16 + sl]);
}

// ---------------------------------------------------------------------------
extern "C" void kernel_launch(void* const* d_in, const int* in_sizes, int n_in,
                              void* d_out, int out_size, void* d_ws, size_t ws_size,
                              hipStream_t stream) {
    const float* M  = (const float*)d_in[0];
    const float* a  = (const float*)d_in[1];
    const int* eidx = (const int*)d_in[2];   // [2, E] flat: src row, dest row
    const int* rev  = (const int*)d_in[3];
    const int N = 50000;
    const int E = in_sizes[3];

    const int* src  = eidx;
    const int* dest = eidx + E;

    // Workspace: Mv[N*64] | score[E] | alpha[E] | sorted_eid[E] |
    //            counts[N] + total[4] | offsets[N] | cursor[N]     ~= 23 MB
    char* ws = (char*)d_ws;
    float* Mv        = (float*)ws; ws += (size_t)N * 64 * 4;
    float* score     = (float*)ws; ws += (size_t)E * 4;
    float* alpha     = (float*)ws; ws += (size_t)E * 4;
    int*   sorted_eid= (int*)ws;   ws += (size_t)E * 4;
    int*   counts    = (int*)ws;   ws += (size_t)(N + 4) * 4;  // +total
    int*   offsets   = (int*)ws;   ws += (size_t)N * 4;
    int*   cursor    = (int*)ws;   ws += (size_t)N * 4;
    int*   total     = counts + N;

    long long tE16 = (long long)E * 16;
    int blocksE16 = (int)((tE16 + THREADS - 1) / THREADS);
    int blocksE   = (E + THREADS - 1) / THREADS;
    int blocksN   = (N + THREADS - 1) / THREADS;
    int blocksN64 = (int)(((long long)N * 64 + THREADS - 1) / THREADS);
    int n4        = (N + 4) / 4;               // counts + total, N mult of 4
    int blocksZ   = (n4 + THREADS - 1) / THREADS;

    k_zero<<<blocksZ, THREADS, 0, stream>>>((int4*)counts, n4);
    k_score_hist<<<blocksE16, THREADS, 0, stream>>>(
        (const float4*)M, (const float4*)a, dest, score, counts, E);
    k_alloc<<<blocksN, THREADS, 0, stream>>>(counts, total, offsets, cursor, N);
    k_fill<<<blocksE, THREADS, 0, stream>>>(dest, cursor, sorted_eid, E);
    k_aggregate<<<blocksN64, THREADS, 0, stream>>>(
        (const float4*)M, score, sorted_eid, offsets, counts,
        (float4*)Mv, alpha, N);
    k_out<<<blocksE16, THREADS, 0, stream>>>(
        (const float4*)M, (const float4*)Mv, alpha, src, rev,
        (f32x4*)d_out, E);
}

// Round 9
// 259.165 us; speedup vs baseline: 3.4638x; 1.0292x over previous
//
#include <hip/hip_runtime.h>
#include <float.h>

// AttentionAgg via destination-CSR (no float atomics).
//   score = M @ a; smax = segmax(score,dest); ex = exp(score-smax[dest])
//   denom = segsum(ex,dest); alpha = ex/denom[dest]
//   Mv = segsum(alpha*M, dest); out = Mv[src] - alpha[rev]*M[rev]
//
// E = 800000, d = 64, N = 50000 (dim_size is a device scalar; hardcoded).
//
// Round-7 -> 8 deltas (resubmitted round 9; round-8 bench was an infra
// failure, kernel never ran):
//  (1) k_fill folded into the score pass (k_score_fill): lane0 allocates the
//      CSR slot and writes sorted_eid AND sorted_score. One fewer E-pass.
//  (2) histogram moved to a cheap dest-only kernel (k_hist, 3.2MB).
//  (3) k_aggregate reads sorted_score/sorted_eid COALESCED (no indirect
//      score gather); score[] array deleted.

#define THREADS 256

typedef float f32x4 __attribute__((ext_vector_type(4)));

// ---------------------------------------------------------------------------
// K0: zero counts[N] + total counter (N+4 ints, multiple of 4).
__global__ void k_zero(int4* __restrict__ p, int n4) {
    int i = blockIdx.x * blockDim.x + threadIdx.x;
    if (i < n4) p[i] = make_int4(0, 0, 0, 0);
}

// ---------------------------------------------------------------------------
// K1: histogram of dest (reads 3.2MB only).
__global__ void k_hist(const int* __restrict__ dest,
                       int* __restrict__ counts, int E) {
    int e = blockIdx.x * blockDim.x + threadIdx.x;
    if (e >= E) return;
    atomicAdd(&counts[dest[e]], 1);
}

// ---------------------------------------------------------------------------
// K2: range allocation. Wave-level exclusive prefix over counts + one
// atomicAdd(total) per wave -> offsets[n], cursor[n].
__global__ void k_alloc(const int* __restrict__ counts,
                        int* __restrict__ total,
                        int* __restrict__ offsets,
                        int* __restrict__ cursor,
                        int N) {
    int n    = blockIdx.x * blockDim.x + threadIdx.x;
    int lane = threadIdx.x & 63;
    int c = (n < N) ? counts[n] : 0;
    int x = c;
    #pragma unroll
    for (int off = 1; off < 64; off <<= 1) {
        int y = __shfl_up(x, off, 64);
        if (lane >= off) x += y;
    }
    int wsum = __shfl(x, 63, 64);
    int base = 0;
    if (lane == 63) base = atomicAdd(total, wsum);
    base = __shfl(base, 63, 64);
    if (n < N) {
        int my = base + x - c;                 // exclusive position
        offsets[n] = my;
        cursor[n]  = my;
    }
}

// ---------------------------------------------------------------------------
// K3: fused score + bucket fill. 16 lanes/edge, float4 loads.
// score = dot(M[e,:], a); lane0: pos = cursor[dest]++; write sorted_eid[pos]
// and sorted_score[pos].
__global__ void k_score_fill(const float4* __restrict__ M4,
                             const float4* __restrict__ a4,
                             const int* __restrict__ dest,
                             int* __restrict__ cursor,
                             int* __restrict__ sorted_eid,
                             float* __restrict__ sorted_score,
                             int E) {
    long long gid = (long long)blockIdx.x * blockDim.x + threadIdx.x;
    int e  = (int)(gid >> 4);
    int sl = (int)(gid & 15);
    if (e >= E) return;
    float4 m  = M4[(size_t)e * 16 + sl];
    float4 av = a4[sl];                        // 256B, L1-resident
    float v = m.x * av.x + m.y * av.y + m.z * av.z + m.w * av.w;
    v += __shfl_xor(v, 1, 64);
    v += __shfl_xor(v, 2, 64);
    v += __shfl_xor(v, 4, 64);
    v += __shfl_xor(v, 8, 64);
    if (sl == 0) {
        int pos = atomicAdd(&cursor[dest[e]], 1);
        sorted_eid[pos]   = e;
        sorted_score[pos] = v;
    }
}

// ---------------------------------------------------------------------------
// K4: one wave per node; writes Mv row AND per-edge alpha.
// Fast path (deg<=64): lane loads (eid, score) COALESCED from the sorted
// arrays; wave-reduce max and exp-sum in registers; weighted pass uses a
// WAVE-UNIFORM trip count so every __shfl executes with all lanes active
// (round-5 lesson). Fallback (deg>64): two-pass, also on sorted arrays.
__global__ void k_aggregate(const float4* __restrict__ M4,
                            const float* __restrict__ sorted_score,
                            const int* __restrict__ sorted_eid,
                            const int* __restrict__ offsets,
                            const int* __restrict__ counts,
                            float4* __restrict__ Mv4,
                            float* __restrict__ alpha,
                            int N) {
    long long gid = (long long)blockIdx.x * blockDim.x + threadIdx.x;
    int n    = (int)(gid >> 6);
    int lane = (int)(gid & 63);
    if (n >= N) return;
    int beg = offsets[n];
    int deg = counts[n];
    int end = beg + deg;
    int grp = lane >> 4;
    int sl  = lane & 15;

    float4 acc = make_float4(0.f, 0.f, 0.f, 0.f);

    if (deg <= 64) {
        int   eid = 0;
        float sc  = -FLT_MAX;
        if (lane < deg) {
            eid = sorted_eid[beg + lane];      // coalesced
            sc  = sorted_score[beg + lane];    // coalesced
        }
        float m = sc;
        #pragma unroll
        for (int off = 32; off; off >>= 1)
            m = fmaxf(m, __shfl_xor(m, off, 64));
        float exr = (lane < deg) ? expf(sc - m) : 0.f;
        float ds  = exr;
        #pragma unroll
        for (int off = 32; off; off >>= 1)
            ds += __shfl_xor(ds, off, 64);
        float inv = ds > 0.f ? 1.0f / ds : 0.0f;
        if (lane < deg) alpha[eid] = exr * inv;     // fused k_alpha
        // wave-uniform trip count; shfl src lane i = grp+4k <= 63, active.
        int iters = (deg + 3) >> 2;
        for (int k = 0; k < iters; ++k) {
            int i = grp + 4 * k;
            float ex = __shfl(exr, i, 64);
            int   e  = __shfl(eid, i, 64);
            if (i < deg) {
                float4 mm = M4[(size_t)e * 16 + sl];
                acc.x += ex * mm.x;
                acc.y += ex * mm.y;
                acc.z += ex * mm.z;
                acc.w += ex * mm.w;
            }
        }
        acc.x += __shfl_xor(acc.x, 16, 64);  acc.x += __shfl_xor(acc.x, 32, 64);
        acc.y += __shfl_xor(acc.y, 16, 64);  acc.y += __shfl_xor(acc.y, 32, 64);
        acc.z += __shfl_xor(acc.z, 16, 64);  acc.z += __shfl_xor(acc.z, 32, 64);
        acc.w += __shfl_xor(acc.w, 16, 64);  acc.w += __shfl_xor(acc.w, 32, 64);
        if (lane < 16) {
            float4 o;
            o.x = acc.x * inv; o.y = acc.y * inv;
            o.z = acc.z * inv; o.w = acc.w * inv;
            Mv4[(size_t)n * 16 + lane] = o;
        }
    } else {
        float m = -FLT_MAX;
        for (int i = beg + lane; i < end; i += 64)
            m = fmaxf(m, sorted_score[i]);
        #pragma unroll
        for (int off = 32; off; off >>= 1)
            m = fmaxf(m, __shfl_xor(m, off, 64));
        float dsum = 0.f;
        for (int i = beg + grp; i < end; i += 4) {
            int e = sorted_eid[i];
            float ex = expf(sorted_score[i] - m);
            if (sl == 0) dsum += ex;
            float4 mm = M4[(size_t)e * 16 + sl];
            acc.x += ex * mm.x;
            acc.y += ex * mm.y;
            acc.z += ex * mm.z;
            acc.w += ex * mm.w;
        }
        dsum += __shfl_xor(dsum, 16, 64);
        dsum += __shfl_xor(dsum, 32, 64);
        float dtot = __shfl(dsum, 0, 64);
        float inv = dtot > 0.f ? 1.0f / dtot : 0.0f;
        for (int i = beg + lane; i < end; i += 64) {
            alpha[sorted_eid[i]] = expf(sorted_score[i] - m) * inv;
        }
        acc.x += __shfl_xor(acc.x, 16, 64);  acc.x += __shfl_xor(acc.x, 32, 64);
        acc.y += __shfl_xor(acc.y, 16, 64);  acc.y += __shfl_xor(acc.y, 32, 64);
        acc.z += __shfl_xor(acc.z, 16, 64);  acc.z += __shfl_xor(acc.z, 32, 64);
        acc.w += __shfl_xor(acc.w, 16, 64);  acc.w += __shfl_xor(acc.w, 32, 64);
        if (lane < 16) {
            float4 o;
            o.x = acc.x * inv; o.y = acc.y * inv;
            o.z = acc.z * inv; o.w = acc.w * inv;
            Mv4[(size_t)n * 16 + lane] = o;
        }
    }
}

// ---------------------------------------------------------------------------
// K5: 16 lanes/edge. out = Mv[src] - alpha[rev] * M[rev]. Per-lane
// same-address scalar loads (HW broadcast). Nontemporal store so the 205MB
// out-stream doesn't evict M from L3.
__global__ void k_out(const float4* __restrict__ M4,
                      const float4* __restrict__ Mv4,
                      const float* __restrict__ alpha,
                      const int* __restrict__ src,
                      const int* __restrict__ rev,
                      f32x4* __restrict__ out4,
                      int E) {
    long long gid = (long long)blockIdx.x * blockDim.x + threadIdx.x;
    int e  = (int)(gid >> 4);
    int sl = (int)(gid & 15);
    if (e >= E) return;
    int s    = src[e];
    int r    = rev[e];
    float al = alpha[r];
    float4 mv = Mv4[(size_t)s * 16 + sl];
    float4 mr = M4[(size_t)r * 16 + sl];
    f32x4 o;
    o.x = mv.x - al * mr.x;
    o.y = mv.y - al * mr.y;
    o.z = mv.z - al * mr.z;
    o.w = mv.w - al * mr.w;
    __builtin_nontemporal_store(o, &out4[(size_t)e * 16 + sl]);
}

// ---------------------------------------------------------------------------
extern "C" void kernel_launch(void* const* d_in, const int* in_sizes, int n_in,
                              void* d_out, int out_size, void* d_ws, size_t ws_size,
                              hipStream_t stream) {
    const float* M  = (const float*)d_in[0];
    const float* a  = (const float*)d_in[1];
    const int* eidx = (const int*)d_in[2];   // [2, E] flat: src row, dest row
    const int* rev  = (const int*)d_in[3];
    const int N = 50000;
    const int E = in_sizes[3];

    const int* src  = eidx;
    const int* dest = eidx + E;

    // Workspace: Mv[N*64] | sorted_score[E] | alpha[E] | sorted_eid[E] |
    //            counts[N]+total[4] | offsets[N] | cursor[N]
    char* ws = (char*)d_ws;
    float* Mv          = (float*)ws; ws += (size_t)N * 64 * 4;
    float* sorted_score= (float*)ws; ws += (size_t)E * 4;
    float* alpha       = (float*)ws; ws += (size_t)E * 4;
    int*   sorted_eid  = (int*)ws;   ws += (size_t)E * 4;
    int*   counts      = (int*)ws;   ws += (size_t)(N + 4) * 4;  // +total
    int*   offsets     = (int*)ws;   ws += (size_t)N * 4;
    int*   cursor      = (int*)ws;   ws += (size_t)N * 4;
    int*   total       = counts + N;

    long long tE16 = (long long)E * 16;
    int blocksE16 = (int)((tE16 + THREADS - 1) / THREADS);
    int blocksE   = (E + THREADS - 1) / THREADS;
    int blocksN   = (N + THREADS - 1) / THREADS;
    int blocksN64 = (int)(((long long)N * 64 + THREADS - 1) / THREADS);
    int n4        = (N + 4) / 4;               // counts + total
    int blocksZ   = (n4 + THREADS - 1) / THREADS;

    k_zero<<<blocksZ, THREADS, 0, stream>>>((int4*)counts, n4);
    k_hist<<<blocksE, THREADS, 0, stream>>>(dest, counts, E);
    k_alloc<<<blocksN, THREADS, 0, stream>>>(counts, total, offsets, cursor, N);
    k_score_fill<<<blocksE16, THREADS, 0, stream>>>(
        (const float4*)M, (const float4*)a, dest, cursor,
        sorted_eid, sorted_score, E);
    k_aggregate<<<blocksN64, THREADS, 0, stream>>>(
        (const float4*)M, sorted_score, sorted_eid, offsets, counts,
        (float4*)Mv, alpha, N);
    k_out<<<blocksE16, THREADS, 0, stream>>>(
        (const float4*)M, (const float4*)Mv, alpha, src, rev,
        (f32x4*)d_out, E);
}